// Round 6
// baseline (221.797 us; speedup 1.0000x reference)
//
#include <hip/hip_runtime.h>
#include <hip/hip_fp16.h>
#include <math.h>

#define NX   160
#define N2   25600        // 160*160
#define N3   4096000      // 160^3
#define NB   4

#define YCH  20           // y-chunk height per thread in conv_xy
#define NBLK_XY 800       // 40 x4 * 160 z * 8 yc * 4 b / 256
#define BLKS_PER_B_XY 200
#define NBLK_Z 800        // 40 x4 * 160 y * 8 zc * 4 b / 256

// 1D Gaussian taps exp(-d^2/50), d=-4..4 (NOT normalized, matches reference)
__device__ __constant__ float G1[9] = {
    0.72614903f, 0.83527021f, 0.92311635f, 0.98019867f, 1.0f,
    0.98019867f, 0.92311635f, 0.83527021f, 0.72614903f};

// edge sums: FULL - missing taps at low/high boundary
#define ES_FULL 7.92946852f
__device__ __constant__ float ES_M[4] = {3.46473426f, 2.48453559f, 1.56141924f,
                                         0.72614903f};
__device__ inline float edge_sum(int i) {
    float s = ES_FULL;
    if (i < 4) s -= ES_M[i];
    if (i > NX - 5) s -= ES_M[NX - 1 - i];
    return s;
}

__device__ inline float4 f4_zero() { return make_float4(0.f, 0.f, 0.f, 0.f); }
__device__ inline float4 f4_axpy(float a, float4 b, float4 c) {
    return make_float4(c.x + a * b.x, c.y + a * b.y, c.z + a * b.z, c.w + a * b.w);
}

__device__ inline float4 load_t4(const __half* p) {
    uint2 u = *(const uint2*)p;
    __half2 a = *(const __half2*)&u.x;
    __half2 b = *(const __half2*)&u.y;
    float2 fa = __half22float2(a);
    float2 fb = __half22float2(b);
    return make_float4(fa.x, fa.y, fb.x, fb.y);
}

// x-conv of one row from 3 raw float4s
__device__ inline float4 xconv9(float4 a, float4 b, float4 c) {
    float w[12] = {a.x, a.y, a.z, a.w, b.x, b.y, b.z, b.w, c.x, c.y, c.z, c.w};
    float4 o = f4_zero();
#pragma unroll
    for (int d = 0; d < 9; ++d) {
        float g = G1[d];
        o.x += g * w[d];
        o.y += g * w[d + 1];
        o.z += g * w[d + 2];
        o.w += g * w[d + 3];
    }
    return o;
}

// block = 256 threads (4 waves). Reduce NV doubles, plain store (NO atomics,
// NO fences — R4 showed per-block __threadfence+ticket costs ~600us).
template <int NV>
__device__ inline void block_reduce_store(double* vals, double* dst) {
    __shared__ double red[4][NV];
    int lane = threadIdx.x & 63;
    int wave = threadIdx.x >> 6;
#pragma unroll
    for (int v = 0; v < NV; ++v) {
        double x = vals[v];
#pragma unroll
        for (int off = 32; off > 0; off >>= 1) x += __shfl_down(x, off, 64);
        if (lane == 0) red[wave][v] = x;
    }
    __syncthreads();
    if (threadIdx.x < NV) {
        int v = threadIdx.x;
        dst[v] = red[0][v] + red[1][v] + red[2][v] + red[3][v];
    }
}

// Column sliding-window x+y conv: no LDS, no barriers. Each thread owns one
// float4 x-column (x4,z,b) for a y-chunk of 20 rows. win[9] holds x-conv
// results of rows y-4..y+4; advance computes x-conv of row y+5 from 3 global
// float4 loads (x-overlap served by L1 within the wave). t stored fp16.
// Fused per-batch partial sums (sum p, sum in*p, sum in) -> pS[bid*3+v].
__global__ __launch_bounds__(256) void conv_xy_kernel(
    const float* __restrict__ labels, const float* __restrict__ inputs,
    __half* __restrict__ t, double* __restrict__ pS) {
    int tid = threadIdx.x;
    int tidg = blockIdx.x * 256 + tid;   // 0 .. 204799
    int x4 = tidg % 40;
    int r = tidg / 40;
    int z = r % NX;
    r /= NX;
    int yc = r % 8;                      // y-chunk
    int b = r / 8;                       // block-uniform (6400 threads per (yc,b))
    int y0 = yc * YCH;

    bool v0 = (x4 > 0);                  // left float4 of window valid
    bool v2 = (x4 < 39);                 // right float4 valid
    int colbase = b * N3 + z * N2 + 4 * x4;
    const float* rowp = labels + colbase;
    const float* inp = inputs + colbase;

    // init window: x-conv of rows y0-4 .. y0+4
    float4 win[9];
#pragma unroll
    for (int d = 0; d < 9; ++d) {
        int gy = y0 - 4 + d;
        if (gy >= 0 && gy < NX) {
            const float* p = rowp + gy * NX;
            float4 a = v0 ? *(const float4*)(p - 4) : f4_zero();
            float4 bb = *(const float4*)p;
            float4 c = v2 ? *(const float4*)(p + 4) : f4_zero();
            win[d] = xconv9(a, bb, c);
        } else {
            win[d] = f4_zero();
        }
    }

    float sp = 0.f, sip = 0.f, si = 0.f;
#pragma unroll
    for (int g = 0; g < YCH / 4; ++g) {
        int yb = y0 + 4 * g;
        // prefetch: raw label rows yb+5..yb+8 (for window advance) and
        // center p/in rows yb..yb+3 (for sums) — up to 20 loads in flight
        float4 ra[4], rb[4], rc[4], pv[4], iv[4];
#pragma unroll
        for (int j = 0; j < 4; ++j) {
            int rr = yb + 5 + j;         // rr >= 5, may exceed 159
            bool vr = (rr < NX);
            const float* p = rowp + rr * NX;
            ra[j] = (vr && v0) ? *(const float4*)(p - 4) : f4_zero();
            rb[j] = vr ? *(const float4*)p : f4_zero();
            rc[j] = (vr && v2) ? *(const float4*)(p + 4) : f4_zero();
            pv[j] = *(const float4*)(rowp + (yb + j) * NX);
            iv[j] = *(const float4*)(inp + (yb + j) * NX);
        }
#pragma unroll
        for (int j = 0; j < 4; ++j) {
            // y-conv
            float4 o = f4_zero();
#pragma unroll
            for (int d = 0; d < 9; ++d) o = f4_axpy(G1[d], win[d], o);
            int gi = colbase + (yb + j) * NX;
            __half2 ha = __floats2half2_rn(o.x, o.y);
            __half2 hb = __floats2half2_rn(o.z, o.w);
            uint2 u;
            u.x = *(unsigned int*)&ha;
            u.y = *(unsigned int*)&hb;
            *(uint2*)&t[gi] = u;

            sp += pv[j].x + pv[j].y + pv[j].z + pv[j].w;
            sip += iv[j].x * pv[j].x + iv[j].y * pv[j].y +
                   iv[j].z * pv[j].z + iv[j].w * pv[j].w;
            si += iv[j].x + iv[j].y + iv[j].z + iv[j].w;

            // advance window with x-conv of row yb+5+j
            float4 nx = xconv9(ra[j], rb[j], rc[j]);
#pragma unroll
            for (int d = 0; d < 8; ++d) win[d] = win[d + 1];
            win[8] = nx;
        }
    }
    double vals[3] = {(double)sp, (double)sip, (double)si};
    block_reduce_store<3>(vals, pS + 3 * blockIdx.x);
}

// one block per batch: sum 200 per-block partials -> S[3b+v]
__global__ __launch_bounds__(256) void reduce_S_kernel(
    const double* __restrict__ pS, double* __restrict__ S) {
    int b = blockIdx.x;
    double v0 = 0, v1 = 0, v2 = 0;
    for (int i = threadIdx.x; i < BLKS_PER_B_XY; i += 256) {
        const double* p = pS + 3 * (b * BLKS_PER_B_XY + i);
        v0 += p[0]; v1 += p[1]; v2 += p[2];
    }
    double vals[3] = {v0, v1, v2};
    block_reduce_store<3>(vals, S + 3 * b);
}

// z-conv via register sliding window (float4 = 4 x-cols), t in fp16, batched
// loads (4 z-steps, 12 loads in flight). Per-block partials -> pZ (plain store).
__global__ __launch_bounds__(256) void conv_z_kernel(
    const __half* __restrict__ t, const float* __restrict__ labels,
    const float* __restrict__ inputs, const double* __restrict__ S,
    double* __restrict__ pZ) {
    int tid = threadIdx.x;
    int tidg = blockIdx.x * 256 + tid;  // 0 .. 204799
    int x4 = tidg % 40;           // float4 column; x = 4*x4
    int r = tidg / 40;
    int y = r % NX;
    r /= NX;
    int zc = r % 8;               // z chunk of 20
    int b = r / 8;

    // per-batch means (class 0: p, class 1: 1-p)
    double sp = S[3 * b + 0], sip = S[3 * b + 1], si = S[3 * b + 2];
    const double Nv = (double)N3;
    float m0 = (float)((sip / Nv) / (sp / Nv + 1e-5));
    float m1 = (float)(((si - sip) / Nv) / ((Nv - sp) / Nv + 1e-5));

    int x = x4 * 4;
    float ey = edge_sum(y);
    float cx[4] = {edge_sum(x) * ey, edge_sum(x + 1) * ey,
                   edge_sum(x + 2) * ey, edge_sum(x + 3) * ey};

    int z0 = zc * 20;
    int base = b * N3 + y * NX + x;

    float4 win[9];
#pragma unroll
    for (int d = 0; d < 9; ++d) {
        int z = z0 - 4 + d;
        win[d] = (z >= 0 && z < NX) ? load_t4(&t[base + z * N2]) : f4_zero();
    }

    float n0 = 0.f, d0 = 0.f, n1 = 0.f, d1 = 0.f;
    for (int zb5 = 0; zb5 < 5; ++zb5) {
        int z = z0 + 4 * zb5;
        float4 tn[4], pv[4], iv[4];
#pragma unroll
        for (int j = 0; j < 4; ++j) {
            int zl = z + j + 5;
            tn[j] = (zl < NX) ? load_t4(&t[base + zl * N2]) : f4_zero();
            int gi = base + (z + j) * N2;
            pv[j] = *(const float4*)&labels[gi];
            iv[j] = *(const float4*)&inputs[gi];
        }
#pragma unroll
        for (int j = 0; j < 4; ++j) {
            float4 c4 = f4_zero();
#pragma unroll
            for (int d = 0; d < 9; ++d) c4 = f4_axpy(G1[d], win[d], c4);
            float ez = edge_sum(z + j);
            float pc[4] = {pv[j].x, pv[j].y, pv[j].z, pv[j].w};
            float ic[4] = {iv[j].x, iv[j].y, iv[j].z, iv[j].w};
            float cc[4] = {c4.x, c4.y, c4.z, c4.w};
#pragma unroll
            for (int l = 0; l < 4; ++l) {
                float c1 = cx[l] * ez - cc[l];  // conv(1-p) via conv(ones)
                float df0 = ic[l] - m0; df0 *= df0;
                float w0 = __expf(-df0 * df0);
                float df1 = ic[l] - m1; df1 *= df1;
                float w1 = __expf(-df1 * df1);
                n0 += cc[l] * pc[l] * w0;
                d0 += cc[l] * w0;
                n1 += c1 * (1.f - pc[l]) * w1;
                d1 += c1 * w1;
            }
#pragma unroll
            for (int d = 0; d < 8; ++d) win[d] = win[d + 1];
            win[8] = tn[j];
        }
    }
    double vals[4] = {(double)n0, (double)d0, (double)n1, (double)d1};
    block_reduce_store<4>(vals, pZ + 4 * blockIdx.x);
}

// single block: sum 800 per-block partials, compute final loss
__global__ __launch_bounds__(256) void finalize_kernel(
    const double* __restrict__ pZ, float* __restrict__ out) {
    double a0 = 0, a1 = 0, a2 = 0, a3 = 0;
    for (int i = threadIdx.x; i < NBLK_Z; i += 256) {
        const double* p = &pZ[4 * i];
        a0 += p[0]; a1 += p[1]; a2 += p[2]; a3 += p[3];
    }
    __shared__ double red[4][4];
    int lane = threadIdx.x & 63;
    int wave = threadIdx.x >> 6;
    double vals[4] = {a0, a1, a2, a3};
#pragma unroll
    for (int v = 0; v < 4; ++v) {
        double x = vals[v];
#pragma unroll
        for (int off = 32; off > 0; off >>= 1) x += __shfl_down(x, off, 64);
        if (lane == 0) red[wave][v] = x;
    }
    __syncthreads();
    if (threadIdx.x == 0) {
        double acc[4];
#pragma unroll
        for (int v = 0; v < 4; ++v)
            acc[v] = red[0][v] + red[1][v] + red[2][v] + red[3][v];
        double r0 = fabs(acc[0] / (acc[1] + 1e-6));
        double r1 = fabs(acc[2] / (acc[3] + 1e-6));
        out[0] = (float)(2.0 - r0 - r1);
    }
}

extern "C" void kernel_launch(void* const* d_in, const int* in_sizes, int n_in,
                              void* d_out, int out_size, void* d_ws, size_t ws_size,
                              hipStream_t stream) {
    const float* labels = (const float*)d_in[0];
    const float* inputs = (const float*)d_in[1];
    float* out = (float*)d_out;

    // ws layout:
    //   [0)       pS : 800*3 doubles = 19200 B
    //   [19200)   S  : 12 doubles
    //   [19456)   pZ : 800*4 doubles = 25600 B
    //   [524288)  t  : 160^3 halves = 8,192,000 B
    double* pS = (double*)d_ws;
    double* S  = (double*)((char*)d_ws + 19200);
    double* pZ = (double*)((char*)d_ws + 19456);
    __half* t  = (__half*)((char*)d_ws + 524288);

    hipLaunchKernelGGL(conv_xy_kernel, dim3(NBLK_XY), dim3(256), 0, stream,
                       labels, inputs, t, pS);
    hipLaunchKernelGGL(reduce_S_kernel, dim3(NB), dim3(256), 0, stream, pS, S);
    hipLaunchKernelGGL(conv_z_kernel, dim3(NBLK_Z), dim3(256), 0, stream,
                       t, labels, inputs, S, pZ);
    hipLaunchKernelGGL(finalize_kernel, dim3(1), dim3(256), 0, stream, pZ, out);
}